// Round 1
// baseline (421.078 us; speedup 1.0000x reference)
//
#include <hip/hip_runtime.h>
#include <math.h>

#define EPS_F 1e-5f
#define NPOINTS 550   // sum_{i=1..10} 10*i
#define CIN 512

// jax.nn.softplus(z) = max(z,0) + log1p(exp(-|z|))
static __device__ __forceinline__ float softplus_f(float z) {
    return fmaxf(z, 0.0f) + log1pf(expf(-fabsf(z)));
}

static __device__ __forceinline__ float dot8(const float4 a0, const float4 a1,
                                             const float4 w0, const float4 w1) {
    float s = a0.x * w0.x;
    s = fmaf(a0.y, w0.y, s);
    s = fmaf(a0.z, w0.z, s);
    s = fmaf(a0.w, w0.w, s);
    s = fmaf(a1.x, w1.x, s);
    s = fmaf(a1.y, w1.y, s);
    s = fmaf(a1.z, w1.z, s);
    s = fmaf(a1.w, w1.w, s);
    return s;
}

__global__ __launch_bounds__(256, 4) void beta_unimodal_kernel(
    const float* __restrict__ x,
    const float* __restrict__ Wa, const float* __restrict__ ba,
    const float* __restrict__ Wb, const float* __restrict__ bb,
    float* __restrict__ out)
{
    // Quadrature table: (log2(g), log2(1-g)) for the 550 grid points,
    // thresholds i=1..10, n_i = 10*i, grid = linspace(EPS, i/10-EPS, n_i).
    __shared__ float2 tab[NPOINTS];

    const int tid = threadIdx.x;

    for (int p = tid; p < NPOINTS; p += 256) {
        int i = 1, off = 0;
        while (p >= off + 10 * i) { off += 10 * i; ++i; }
        const int j = p - off;
        const int n = 10 * i;
        const float thr = (float)i * 0.1f;
        const float step = (thr - 2.0f * EPS_F) / (float)(n - 1);
        const float g = EPS_F + step * (float)j;          // matches jnp.linspace f32
        float2 e;
        e.x = log2f(g);
        e.y = log2f(1.0f - g);   // exact subtraction for g>=0.5 (Sterbenz)
        tab[p] = e;
    }
    __syncthreads();

    const int lane = tid & 63;
    const int wave = tid >> 6;                       // 0..3
    const long rowBase = ((long)blockIdx.x * 4 + wave) * 64;

    // W vectors live in registers: lane l owns cols [4l..4l+3] and [256+4l..+3]
    const float4* Wa4 = (const float4*)Wa;
    const float4* Wb4 = (const float4*)Wb;
    const float4 wa0 = Wa4[lane], wa1 = Wa4[64 + lane];
    const float4 wb0 = Wb4[lane], wb1 = Wb4[64 + lane];

    // ---- Phase 1: wave-per-row dual GEMV dot; lane r keeps row r's sums ----
    float my_da = 0.0f, my_db = 0.0f;

    for (int r0 = 0; r0 < 64; r0 += 4) {
        float4 xs0[4], xs1[4];
        #pragma unroll
        for (int u = 0; u < 4; ++u) {
            const float4* xr = (const float4*)(x + (rowBase + r0 + u) * CIN);
            xs0[u] = xr[lane];        // cols 0..255, coalesced 1KB/wave
            xs1[u] = xr[64 + lane];   // cols 256..511
        }
        #pragma unroll
        for (int u = 0; u < 4; ++u) {
            float da = dot8(xs0[u], xs1[u], wa0, wa1);
            float db = dot8(xs0[u], xs1[u], wb0, wb1);
            #pragma unroll
            for (int s = 32; s > 0; s >>= 1) {
                da += __shfl_xor(da, s, 64);
                db += __shfl_xor(db, s, 64);
            }
            if (lane == r0 + u) { my_da = da; my_db = db; }
        }
    }

    // ---- Phase 2: thread-per-row quadrature (lane l owns row rowBase+l) ----
    const float za = my_da + ba[0];
    const float zb = my_db + bb[0];
    const float alpha = fminf(fmaxf(1.0f + softplus_f(za), 1.0f), 100.0f);
    const float beta  = fminf(fmaxf(1.0f + softplus_f(zb), 1.0f), 100.0f);
    const float am1 = alpha - 1.0f;
    const float bm1 = beta - 1.0f;

    // Stabilizer: M2 = max_g [am1*log2(g) + bm1*log2(1-g)] at the mode.
    // (lbeta & dx are common factors -> cancel in the normalization; any
    //  common stabilizer M2 also cancels. Concave exponent => e <= 0 always.)
    const float denom = am1 + bm1;
    float mode = (denom > 0.0f) ? (am1 / denom) : 0.5f;
    mode = fminf(fmaxf(mode, 1e-7f), 1.0f - 1.1920929e-7f);
    const float M2 = am1 * log2f(mode) + bm1 * log2f(1.0f - mode);

    float cum[11];
    cum[0] = 0.0f;
    int p = 0;
    #pragma unroll
    for (int i = 1; i <= 10; ++i) {
        const int n = 10 * i;          // always even
        float s0 = 0.0f, s1 = 0.0f;
        for (int j = 0; j < n; j += 2) {
            const float2 t0 = tab[p];
            const float2 t1 = tab[p + 1];
            p += 2;
            const float e0 = fmaf(am1, t0.x, bm1 * t0.y) - M2;
            const float e1 = fmaf(am1, t1.x, bm1 * t1.y) - M2;
            s0 += __builtin_amdgcn_exp2f(e0);
            s1 += __builtin_amdgcn_exp2f(e1);
        }
        cum[i] = s0 + s1;
    }

    const float inv = 1.0f / cum[10];  // sum(probs) = cum[10] - cum[0]
    float* orow = out + (rowBase + lane) * 10;
    #pragma unroll
    for (int k = 0; k < 10; ++k) orow[k] = (cum[k + 1] - cum[k]) * inv;
}

extern "C" void kernel_launch(void* const* d_in, const int* in_sizes, int n_in,
                              void* d_out, int out_size, void* d_ws, size_t ws_size,
                              hipStream_t stream) {
    const float* x  = (const float*)d_in[0];
    const float* Wa = (const float*)d_in[1];
    const float* ba = (const float*)d_in[2];
    const float* Wb = (const float*)d_in[3];
    const float* bb = (const float*)d_in[4];
    float* out = (float*)d_out;

    const int batch = in_sizes[0] / CIN;     // 131072
    const int blocks = batch / 256;          // 4 waves/block * 64 rows/wave
    beta_unimodal_kernel<<<blocks, 256, 0, stream>>>(x, Wa, ba, Wb, bb, out);
}

// Round 2
// 367.363 us; speedup vs baseline: 1.1462x; 1.1462x over previous
//
#include <hip/hip_runtime.h>
#include <math.h>

#define EPS_F 1e-5f
#define NPOINTS 550   // sum_{i=1..10} 10*i
#define CIN 512

// jax.nn.softplus(z) = max(z,0) + log1p(exp(-|z|))
static __device__ __forceinline__ float softplus_f(float z) {
    return fmaxf(z, 0.0f) + log1pf(expf(-fabsf(z)));
}

static __device__ __forceinline__ float dot8(const float4 a0, const float4 a1,
                                             const float4 w0, const float4 w1) {
    float s = a0.x * w0.x;
    s = fmaf(a0.y, w0.y, s);
    s = fmaf(a0.z, w0.z, s);
    s = fmaf(a0.w, w0.w, s);
    s = fmaf(a1.x, w1.x, s);
    s = fmaf(a1.y, w1.y, s);
    s = fmaf(a1.z, w1.z, s);
    s = fmaf(a1.w, w1.w, s);
    return s;
}

// Block = 256 threads (4 waves), 64 rows/block -> grid 2048 = 8 blocks/CU.
__global__ __launch_bounds__(256, 8) void beta_unimodal_kernel(
    const float* __restrict__ x,
    const float* __restrict__ Wa, const float* __restrict__ ba,
    const float* __restrict__ Wb, const float* __restrict__ bb,
    float* __restrict__ out)
{
    // Quadrature table: (log2(g), log2(1-g)) for the 550 grid points of the
    // 10 independent CDF grids: threshold i -> linspace(EPS, i/10-EPS, 10*i).
    __shared__ float2 tab[NPOINTS];
    __shared__ float outbuf[64 * 10];          // staged block output

    const int tid = threadIdx.x;

    for (int p = tid; p < NPOINTS; p += 256) {
        int i = 1, off = 0;
        while (p >= off + 10 * i) { off += 10 * i; ++i; }
        const int j = p - off;
        const int n = 10 * i;
        const float thr = (float)i * 0.1f;
        const float step = (thr - 2.0f * EPS_F) / (float)(n - 1);
        const float g = EPS_F + step * (float)j;          // matches jnp.linspace f32
        float2 e;
        e.x = log2f(g);
        e.y = log2f(1.0f - g);
        tab[p] = e;
    }
    __syncthreads();

    const int lane = tid & 63;
    const int wave = tid >> 6;                            // 0..3
    const long rowBase = (long)blockIdx.x * 64 + wave * 16;

    // W in registers: lane l owns cols [4l..4l+3] and [256+4l..4l+3]
    const float4* Wa4 = (const float4*)Wa;
    const float4* Wb4 = (const float4*)Wb;
    const float4 wa0 = Wa4[lane], wa1 = Wa4[64 + lane];
    const float4 wb0 = Wb4[lane], wb1 = Wb4[64 + lane];

    // ---- Phase 1: wave computes 16 rows' dual dots; 4-lane group g keeps row g
    const int g = lane >> 2;                              // 0..15 row group
    const int q = lane & 3;                               // quarter within group
    float my_da = 0.0f, my_db = 0.0f;

    for (int r0 = 0; r0 < 16; r0 += 4) {
        float4 xs0[4], xs1[4];
        #pragma unroll
        for (int u = 0; u < 4; ++u) {
            const float4* xr = (const float4*)(x + (rowBase + r0 + u) * CIN);
            xs0[u] = xr[lane];        // cols 0..255, 1KB/instr coalesced
            xs1[u] = xr[64 + lane];   // cols 256..511
        }
        #pragma unroll
        for (int u = 0; u < 4; ++u) {
            float da = dot8(xs0[u], xs1[u], wa0, wa1);
            float db = dot8(xs0[u], xs1[u], wb0, wb1);
            #pragma unroll
            for (int s = 32; s > 0; s >>= 1) {
                da += __shfl_xor(da, s, 64);
                db += __shfl_xor(db, s, 64);
            }
            if (g == r0 + u) { my_da = da; my_db = db; }  // all 4 lanes of group
        }
    }

    // ---- Phase 2: 4 lanes per row; lane q sums quadrature points j%4==q ----
    const float za = my_da + ba[0];
    const float zb = my_db + bb[0];
    const float alpha = fminf(fmaxf(1.0f + softplus_f(za), 1.0f), 100.0f);
    const float beta  = fminf(fmaxf(1.0f + softplus_f(zb), 1.0f), 100.0f);
    const float am1 = alpha - 1.0f;
    const float bm1 = beta - 1.0f;

    // Stabilizer at the Beta mode (common positive factors lbeta/dx cancel in
    // the normalization; concave exponent => all exp2 args <= 0).
    const float denom = am1 + bm1;
    float mode = (denom > 0.0f) ? (am1 / denom) : 0.5f;
    mode = fminf(fmaxf(mode, 1e-7f), 1.0f - 1.1920929e-7f);
    const float M2 = am1 * log2f(mode) + bm1 * log2f(1.0f - mode);

    float seg[10];                     // unnormalized CDF at threshold i
    int p0 = 0;
    #pragma unroll
    for (int i = 1; i <= 10; ++i) {
        const int n = 10 * i;
        float s = 0.0f;
        for (int j = q; j < n; j += 4) {
            const float2 t = tab[p0 + j];
            const float e = fmaf(am1, t.x, bm1 * t.y) - M2;
            s += __builtin_amdgcn_exp2f(e);
        }
        // combine the 4 quarters; all 4 lanes end with the full sum
        s += __shfl_xor(s, 1, 64);
        s += __shfl_xor(s, 2, 64);
        seg[i - 1] = s;
        p0 += n;
    }

    const float inv = 1.0f / seg[9];
    const int rowLocal = wave * 16 + g;
    // lane q writes elements k = q, q+4, q+8 (covers 0..9 across the group)
    for (int k = q; k < 10; k += 4) {
        const float prev = (k > 0) ? seg[k - 1] : 0.0f;
        outbuf[rowLocal * 10 + k] = (seg[k] - prev) * inv;
    }
    __syncthreads();

    // ---- Coalesced block write: 640 floats = 160 float4 ----
    if (tid < 160) {
        const float4* src = (const float4*)outbuf;
        float4* dst = (float4*)(out + (size_t)blockIdx.x * 640);
        dst[tid] = src[tid];
    }
}

extern "C" void kernel_launch(void* const* d_in, const int* in_sizes, int n_in,
                              void* d_out, int out_size, void* d_ws, size_t ws_size,
                              hipStream_t stream) {
    const float* x  = (const float*)d_in[0];
    const float* Wa = (const float*)d_in[1];
    const float* ba = (const float*)d_in[2];
    const float* Wb = (const float*)d_in[3];
    const float* bb = (const float*)d_in[4];
    float* out = (float*)d_out;

    const int batch = in_sizes[0] / CIN;     // 131072
    const int blocks = batch / 64;           // 2048 blocks = 8 blocks/CU
    beta_unimodal_kernel<<<blocks, 256, 0, stream>>>(x, Wa, ba, Wb, bb, out);
}

// Round 3
// 362.257 us; speedup vs baseline: 1.1624x; 1.0141x over previous
//
#include <hip/hip_runtime.h>
#include <math.h>

#define EPS_F 1e-5f
#define NPOINTS 550   // sum_{i=1..10} 10*i
#define CIN 512

// jax.nn.softplus(z) = max(z,0) + log1p(exp(-|z|))
static __device__ __forceinline__ float softplus_f(float z) {
    return fmaxf(z, 0.0f) + log1pf(expf(-fabsf(z)));
}

static __device__ __forceinline__ float dot8(const float4 a0, const float4 a1,
                                             const float4 w0, const float4 w1) {
    float s = a0.x * w0.x;
    s = fmaf(a0.y, w0.y, s);
    s = fmaf(a0.z, w0.z, s);
    s = fmaf(a0.w, w0.w, s);
    s = fmaf(a1.x, w1.x, s);
    s = fmaf(a1.y, w1.y, s);
    s = fmaf(a1.z, w1.z, s);
    s = fmaf(a1.w, w1.w, s);
    return s;
}

// Block = 256 threads (4 waves), 8 rows/wave -> 32 rows/block, grid 4096.
// Phase 1 K-loop has NO cross-lane ops: 16 b128 loads + FMA only; the
// reduction is a single per-wave LDS transpose (wave-synchronous, no barrier).
__global__ __launch_bounds__(256, 4) void beta_unimodal_kernel(
    const float* __restrict__ x,
    const float* __restrict__ Wa, const float* __restrict__ ba,
    const float* __restrict__ Wb, const float* __restrict__ bb,
    float* __restrict__ out)
{
    __shared__ float2 tab[NPOINTS];          // (log2 g, log2(1-g)) per point
    __shared__ float outbuf[32 * 10];        // staged block output
    __shared__ float part[4][2][8][68];      // [wave][a/b][row][lane(+pad)]

    const int tid = threadIdx.x;

    for (int p = tid; p < NPOINTS; p += 256) {
        int i = 1, off = 0;
        while (p >= off + 10 * i) { off += 10 * i; ++i; }
        const int j = p - off;
        const int n = 10 * i;
        const float thr = (float)i * 0.1f;
        const float step = (thr - 2.0f * EPS_F) / (float)(n - 1);
        const float g = EPS_F + step * (float)j;          // matches jnp.linspace f32
        float2 e;
        e.x = log2f(g);
        e.y = log2f(1.0f - g);
        tab[p] = e;
    }
    __syncthreads();

    const int lane = tid & 63;
    const int wave = tid >> 6;                            // 0..3
    const long rowBase = (long)blockIdx.x * 32 + wave * 8;

    // W in registers: lane l owns cols [4l..4l+3] and [256+4l..4l+3]
    const float4* Wa4 = (const float4*)Wa;
    const float4* Wb4 = (const float4*)Wb;
    const float4 wa0 = Wa4[lane], wa1 = Wa4[64 + lane];
    const float4 wb0 = Wb4[lane], wb1 = Wb4[64 + lane];

    // ---- Phase 1: pure load+FMA, per-lane partials for 8 rows ----
    float pa[8], pb[8];
    #pragma unroll
    for (int r = 0; r < 8; ++r) {
        const float4* xr = (const float4*)(x + (rowBase + r) * CIN);
        const float4 x0 = xr[lane];       // cols 0..255, 1KB/instr coalesced
        const float4 x1 = xr[64 + lane];  // cols 256..511
        pa[r] = dot8(x0, x1, wa0, wa1);
        pb[r] = dot8(x0, x1, wb0, wb1);
    }

    // ---- Per-wave LDS transpose reduction (no __syncthreads needed) ----
    #pragma unroll
    for (int r = 0; r < 8; ++r) {
        part[wave][0][r][lane] = pa[r];   // 64 consecutive floats: conflict-free
        part[wave][1][r][lane] = pb[r];
    }
    asm volatile("s_waitcnt lgkmcnt(0)" ::: "memory");  // wave-synchronous LDS

    // 8 lanes per row: oct o = lane&7; o<4 sums a-quarter o, o>=4 b-quarter o-4
    const int row = lane >> 3;            // 0..7 (local row)
    const int o = lane & 7;
    const int v = o >> 2;                 // 0 = a, 1 = b
    const int qa = o & 3;                 // quarter of the 64 partials
    const float2* src2 = (const float2*)&part[wave][v][row][qa * 16];
    float s = 0.0f;
    #pragma unroll
    for (int c = 0; c < 8; ++c) {
        const float2 t = src2[c];
        s += t.x + t.y;
    }
    s += __shfl_xor(s, 1, 64);
    s += __shfl_xor(s, 2, 64);            // 4-lane set now holds full v-sum
    const float other = __shfl_xor(s, 4, 64);
    const float my_da = (v == 0) ? s : other;
    const float my_db = (v == 0) ? other : s;

    // ---- Phase 2: 8 lanes per row; lane o sums quadrature points j%8==o ----
    const float za = my_da + ba[0];
    const float zb = my_db + bb[0];
    const float alpha = fminf(fmaxf(1.0f + softplus_f(za), 1.0f), 100.0f);
    const float beta  = fminf(fmaxf(1.0f + softplus_f(zb), 1.0f), 100.0f);
    const float am1 = alpha - 1.0f;
    const float bm1 = beta - 1.0f;

    // Stabilizer at the Beta mode (lbeta & dx are common positive factors and
    // cancel in the normalization; concave exponent => all exp2 args <= 0).
    const float denom = am1 + bm1;
    float mode = (denom > 0.0f) ? (am1 / denom) : 0.5f;
    mode = fminf(fmaxf(mode, 1e-7f), 1.0f - 1.1920929e-7f);
    const float M2 = am1 * log2f(mode) + bm1 * log2f(1.0f - mode);

    float seg[10];                        // unnormalized CDF at threshold i
    int p0 = 0;
    #pragma unroll
    for (int i = 1; i <= 10; ++i) {
        const int n = 10 * i;
        float s2 = 0.0f;
        for (int j = o; j < n; j += 8) {  // broadcast LDS reads, conflict-free
            const float2 t = tab[p0 + j];
            const float e = fmaf(am1, t.x, bm1 * t.y) - M2;
            s2 += __builtin_amdgcn_exp2f(e);
        }
        s2 += __shfl_xor(s2, 1, 64);
        s2 += __shfl_xor(s2, 2, 64);
        s2 += __shfl_xor(s2, 4, 64);      // all 8 lanes of the row get full sum
        seg[i - 1] = s2;
        p0 += n;
    }

    const float inv = 1.0f / seg[9];
    const int rowLocal = wave * 8 + row;  // 0..31
    {   // lane o writes element o; lanes 0,1 also write 8,9
        const float prev = (o > 0) ? seg[o - 1] : 0.0f;
        outbuf[rowLocal * 10 + o] = (seg[o] - prev) * inv;
        if (o < 2) {
            const int k = o + 8;
            outbuf[rowLocal * 10 + k] = (seg[k] - seg[k - 1]) * inv;
        }
    }
    __syncthreads();

    // ---- Coalesced block write: 320 floats = 80 float4 ----
    if (tid < 80) {
        const float4* src = (const float4*)outbuf;
        float4* dst = (float4*)(out + (size_t)blockIdx.x * 320);
        dst[tid] = src[tid];
    }
}

extern "C" void kernel_launch(void* const* d_in, const int* in_sizes, int n_in,
                              void* d_out, int out_size, void* d_ws, size_t ws_size,
                              hipStream_t stream) {
    const float* x  = (const float*)d_in[0];
    const float* Wa = (const float*)d_in[1];
    const float* ba = (const float*)d_in[2];
    const float* Wb = (const float*)d_in[3];
    const float* bb = (const float*)d_in[4];
    float* out = (float*)d_out;

    const int batch = in_sizes[0] / CIN;     // 131072
    const int blocks = batch / 32;           // 4096 blocks, 32 rows each
    beta_unimodal_kernel<<<blocks, 256, 0, stream>>>(x, Wa, ba, Wb, bb, out);
}